// Round 6
// baseline (53.033 us; speedup 1.0000x reference)
//
#include <hip/hip_runtime.h>
#include <math.h>

#define DM 512
#define NH 8
#define HD 64
#define BB 2
#define TT 2048
#define CHUNK 64
#define NC (TT / CHUNK)   /* 32 */
#define BH (BB * NH)      /* 16 */
#define ROWS (BB * TT)    /* 4096 */
#define EPSV 1e-6f

typedef short bf16x8 __attribute__((ext_vector_type(8)));
typedef float f32x4 __attribute__((ext_vector_type(4)));
typedef unsigned short us;

union U4 { us h[4]; uint2 u; };

__device__ __forceinline__ us f2bf(float f) {
    unsigned int u = __float_as_uint(f);
    return (us)((u + 0x7FFFu + ((u >> 16) & 1u)) >> 16);
}
__device__ __forceinline__ float bf2f(us h) {
    return __uint_as_float(((unsigned int)h) << 16);
}
__device__ __forceinline__ void gload16(const void* g, void* l) {
    __builtin_amdgcn_global_load_lds(
        (const __attribute__((address_space(1))) unsigned int*)g,
        (__attribute__((address_space(3))) unsigned int*)l, 16, 0, 0);
}
// XOR swizzle on 16B blocks within a 64-elem bf16 row.
#define SWZ(r, k) ((k) ^ (((r) & 7) << 3))
// swizzle for the 128-elem C^T bounce rows (two 64-elem halves)
#define SWZ128(c, t) (((t) & 64) | (((t) & 63) ^ (((c) & 7) << 3)))

// ---------------------------------------------------------------------------
// prep: blocks [0,2048): x f32 -> xb bf16.  blocks [2048,3072): W -> W^T bf16.
// ---------------------------------------------------------------------------
__global__ __launch_bounds__(256) void prep(
    const float* __restrict__ x,
    const float* __restrict__ Wq, const float* __restrict__ Wk,
    const float* __restrict__ Wv, const float* __restrict__ Wo,
    us* __restrict__ xb, us* __restrict__ WT)
{
    const int bid = blockIdx.x, tid = threadIdx.x;
    __shared__ float tl[32][33];
    if (bid < 2048) {
        const int i = bid * 256 + tid;
        float4 v = ((const float4*)x)[i];
        U4 o;
        o.h[0] = f2bf(v.x); o.h[1] = f2bf(v.y);
        o.h[2] = f2bf(v.z); o.h[3] = f2bf(v.w);
        ((uint2*)xb)[i] = o.u;
    } else {
        const int b2 = bid - 2048;
        const int which = b2 >> 8, t = b2 & 255;
        const float* W = (which == 0) ? Wq : (which == 1) ? Wk : (which == 2) ? Wv : Wo;
        us* O = WT + (size_t)which * DM * DM;
        const int r0 = (t >> 4) * 32, c0 = (t & 15) * 32;
        const int tr = tid >> 3, tc = tid & 7;
        float4 v = *(const float4*)&W[(size_t)(r0 + tr) * DM + c0 + tc * 4];
        tl[tr][tc * 4 + 0] = v.x; tl[tr][tc * 4 + 1] = v.y;
        tl[tr][tc * 4 + 2] = v.z; tl[tr][tc * 4 + 3] = v.w;
        __syncthreads();
        U4 o;
#pragma unroll
        for (int i = 0; i < 4; ++i) o.h[i] = f2bf(tl[tc * 4 + i][tr]);
        *(uint2*)&O[(size_t)(c0 + tr) * DM + r0 + tc * 4] = o.u;
    }
}

// ---------------------------------------------------------------------------
// 128x128 GEMM core (m97 shape): C = A[128xDM] @ B[128xDM]^T, BK=64,
// single-buffered, 2 barriers/K-step, 4 waves (2x2), wave-tile 64x64.
// ---------------------------------------------------------------------------
__device__ __forceinline__ void gemm128(
    const us* __restrict__ Ag, const us* __restrict__ Bg,
    int r0, int c0, int tid, us* As, us* Bs, f32x4 (&acc)[4][4])
{
    const int lane = tid & 63, wid = tid >> 6;
    const int wr = wid >> 1, wc = wid & 1;
    const int lrow = lane & 15, lk8 = (lane >> 4) * 8;
    const int fa = tid * 8;

    for (int k0 = 0; k0 < DM; k0 += 64) {
        __syncthreads();
#pragma unroll
        for (int i = 0; i < 4; ++i) {
            const int f = fa + i * 2048, row = f >> 6, kp = f & 63;
            gload16(Ag + (size_t)(r0 + row) * DM + k0 + SWZ(row, kp), As + f);
            gload16(Bg + (size_t)(c0 + row) * DM + k0 + SWZ(row, kp), Bs + f);
        }
        __syncthreads();
#pragma unroll
        for (int kin = 0; kin < 64; kin += 32) {
            bf16x8 af[4], bfr[4];
#pragma unroll
            for (int mi = 0; mi < 4; ++mi) {
                const int row = wr * 64 + mi * 16 + lrow;
                af[mi] = *(const bf16x8*)&As[row * 64 + SWZ(row, kin + lk8)];
            }
#pragma unroll
            for (int ni = 0; ni < 4; ++ni) {
                const int row = wc * 64 + ni * 16 + lrow;
                bfr[ni] = *(const bf16x8*)&Bs[row * 64 + SWZ(row, kin + lk8)];
            }
#pragma unroll
            for (int mi = 0; mi < 4; ++mi)
#pragma unroll
                for (int ni = 0; ni < 4; ++ni)
                    acc[mi][ni] = __builtin_amdgcn_mfma_f32_16x16x32_bf16(
                        af[mi], bfr[ni], acc[mi][ni], 0, 0, 0);
        }
    }
}

// ---------------------------------------------------------------------------
// QKV projection (128x128 tile).  Q natural; K natural + transposed; V
// transposed.  Transposed outputs go through a swizzled LDS bounce so the
// global stores are 256B-contiguous per (h,d) row (no write amplification).
// ---------------------------------------------------------------------------
__global__ __launch_bounds__(256) void qkv_mfma(
    const us* __restrict__ xb, const us* __restrict__ WT,
    const float* __restrict__ bq, const float* __restrict__ bk,
    const float* __restrict__ bv,
    us* __restrict__ qn, us* __restrict__ kn,
    us* __restrict__ kt, us* __restrict__ vt)
{
    const int which = blockIdx.z;
    const us* Bg = WT + (size_t)which * DM * DM;
    const float* bias = (which == 0) ? bq : (which == 1) ? bk : bv;

    __shared__ us sh[16384];          // staging tiles; reused as C^T bounce
    us* As = sh;
    us* Bs = sh + 8192;
    us* Cb = sh;

    f32x4 acc[4][4] = {};
    const int r0 = blockIdx.x * 128, c0 = blockIdx.y * 128;
    const int tid = threadIdx.x;

    gemm128(xb, Bg, r0, c0, tid, As, Bs, acc);

    const int lane = tid & 63, wid = tid >> 6;
    const int wr = wid >> 1, wc = wid & 1;
    const int lrow = lane & 15, lr4 = (lane >> 4) * 4;
    const int b = r0 >> 11, t0b = r0 & (TT - 1);

    if (which == 0) {
#pragma unroll
        for (int mi = 0; mi < 4; ++mi) {
            const int t = t0b + wr * 64 + mi * 16 + lr4;
#pragma unroll
            for (int ni = 0; ni < 4; ++ni) {
                const int col = c0 + wc * 64 + ni * 16 + lrow;
                const int h = col >> 6, d = col & 63;
                const float bc = bias[col];
#pragma unroll
                for (int r = 0; r < 4; ++r) {
                    float y = acc[mi][ni][r] + bc;
                    y = (y > 0.f) ? (y + 1.f) : __expf(y);
                    qn[((size_t)(b * NH + h) * TT + t + r) * HD + d] = f2bf(y);
                }
            }
        }
        return;
    }

    __syncthreads();                  // done reading As/Bs
#pragma unroll
    for (int mi = 0; mi < 4; ++mi) {
        const int tL = wr * 64 + mi * 16 + lr4;
#pragma unroll
        for (int ni = 0; ni < 4; ++ni) {
            const int colL = wc * 64 + ni * 16 + lrow;
            const int col = c0 + colL;
            const float bc = bias[col];
            U4 p4;
#pragma unroll
            for (int r = 0; r < 4; ++r) {
                float y = acc[mi][ni][r] + bc;
                if (which == 1) y = (y > 0.f) ? (y + 1.f) : __expf(y);
                p4.h[r] = f2bf(y);
            }
            if (which == 1) {
                const int h = col >> 6, d = col & 63;
#pragma unroll
                for (int r = 0; r < 4; ++r)
                    kn[((size_t)(b * NH + h) * TT + t0b + tL + r) * HD + d] = p4.h[r];
            }
            *(uint2*)&Cb[colL * 128 + SWZ128(colL, tL)] = p4.u;
        }
    }
    __syncthreads();

    us* dst = (which == 1) ? kt : vt;
#pragma unroll
    for (int it = 0; it < 8; ++it) {
        const int colL = it * 16 + wid * 4 + (lane >> 4);
        const int tch = (lane & 15) * 8;
        const uint4 v = *(const uint4*)&Cb[colL * 128 + SWZ128(colL, tch)];
        const int col = c0 + colL, h = col >> 6, d = col & 63;
        *(uint4*)&dst[((size_t)(b * NH + h) * HD + d) * TT + t0b + tch] = v;
    }
}

// ---------------------------------------------------------------------------
// Output projection (128x128): out = attn(bf16) @ Wo^T + bo, f32 out.
// ---------------------------------------------------------------------------
__global__ __launch_bounds__(256) void out_mfma(
    const us* __restrict__ Ag, const us* __restrict__ WoT,
    const float* __restrict__ bias, float* __restrict__ out)
{
    __shared__ us sh[16384];
    f32x4 acc[4][4] = {};
    const int r0 = blockIdx.x * 128, c0 = blockIdx.y * 128;
    const int tid = threadIdx.x;

    gemm128(Ag, WoT, r0, c0, tid, sh, sh + 8192, acc);

    const int lane = tid & 63, wid = tid >> 6;
    const int wr = wid >> 1, wc = wid & 1;
    const int lrow = lane & 15, lr4 = (lane >> 4) * 4;

#pragma unroll
    for (int mi = 0; mi < 4; ++mi)
#pragma unroll
        for (int ni = 0; ni < 4; ++ni) {
            const int col = c0 + wc * 64 + ni * 16 + lrow;
            const float bc = bias[col];
#pragma unroll
            for (int r = 0; r < 4; ++r) {
                const int row = r0 + wr * 64 + mi * 16 + lr4 + r;
                out[(size_t)row * DM + col] = acc[mi][ni][r] + bc;
            }
        }
}

// ---------------------------------------------------------------------------
// chunk_sums: LDS-staged.  S^T_c via MFMA; z_c via virtual ones-row MFMA
// (R4-verified) on the wr==0 waves.  Single barrier.
// ---------------------------------------------------------------------------
__global__ __launch_bounds__(256) void chunk_sums(
    const us* __restrict__ kt, const us* __restrict__ vt,
    us* __restrict__ kvc, float* __restrict__ zc)
{
    const int blk = blockIdx.x, bh = blk >> 5, c = blk & 31;
    const int t0 = c * CHUNK;
    __shared__ us Ksl[4096], Vsl[4096];
    const int tid = threadIdx.x;
    const us* ktb = kt + (size_t)bh * HD * TT;
    const us* vtb = vt + (size_t)bh * HD * TT;

#pragma unroll
    for (int i = 0; i < 2; ++i) {
        const int f = tid * 8 + i * 2048, row = f >> 6, kp = f & 63;
        const int kl = SWZ(row, kp);
        gload16(ktb + (size_t)row * TT + t0 + kl, Ksl + f);
        gload16(vtb + (size_t)row * TT + t0 + kl, Vsl + f);
    }
    __syncthreads();

    const int lane = tid & 63, wid = tid >> 6;
    const int wr = wid >> 1, wc = wid & 1;
    const int lrow = lane & 15, lk8 = (lane >> 4) * 8, lr4 = (lane >> 4) * 4;

    bf16x8 onesA = {};
    if (lrow == 0)
#pragma unroll
        for (int e = 0; e < 8; ++e) onesA[e] = (short)0x3F80;

    f32x4 acc[2][2] = {};
    f32x4 accz[2] = {};
#pragma unroll
    for (int kin = 0; kin < 64; kin += 32) {
        bf16x8 af[2], bfr[2];
#pragma unroll
        for (int mi = 0; mi < 2; ++mi) {
            const int row = wr * 32 + mi * 16 + lrow;
            af[mi] = *(const bf16x8*)&Vsl[row * 64 + SWZ(row, kin + lk8)];
        }
#pragma unroll
        for (int ni = 0; ni < 2; ++ni) {
            const int row = wc * 32 + ni * 16 + lrow;
            bfr[ni] = *(const bf16x8*)&Ksl[row * 64 + SWZ(row, kin + lk8)];
        }
#pragma unroll
        for (int mi = 0; mi < 2; ++mi)
#pragma unroll
            for (int ni = 0; ni < 2; ++ni)
                acc[mi][ni] = __builtin_amdgcn_mfma_f32_16x16x32_bf16(
                    af[mi], bfr[ni], acc[mi][ni], 0, 0, 0);
        if (wr == 0)
#pragma unroll
            for (int ni = 0; ni < 2; ++ni)
                accz[ni] = __builtin_amdgcn_mfma_f32_16x16x32_bf16(
                    onesA, bfr[ni], accz[ni], 0, 0, 0);
    }

    us* dst = kvc + (size_t)blk * 4096;
#pragma unroll
    for (int mi = 0; mi < 2; ++mi)
#pragma unroll
        for (int ni = 0; ni < 2; ++ni) {
            const int d2 = wr * 32 + mi * 16 + lr4;
            const int d1 = wc * 32 + ni * 16 + lrow;
#pragma unroll
            for (int r = 0; r < 4; ++r)
                dst[(d2 + r) * 64 + d1] = f2bf(acc[mi][ni][r]);
        }

    if (wr == 0 && lane < 16)
#pragma unroll
        for (int ni = 0; ni < 2; ++ni)
            zc[(size_t)blk * 64 + wc * 32 + ni * 16 + lane] = accz[ni][0];
}

// ---------------------------------------------------------------------------
// scan: exclusive prefix over chunks, register-blocked two-phase.
// ---------------------------------------------------------------------------
__global__ __launch_bounds__(256) void scan(
    const us* __restrict__ kvc, const float* __restrict__ zc,
    us* __restrict__ spr, float* __restrict__ zpr)
{
    const int bh = blockIdx.x, seg = blockIdx.y, tid = threadIdx.x;
    if (seg < 8) {
        const int e = seg * 512 + tid * 2;
        const size_t base = (size_t)(bh * NC) * 4096 + e;
        unsigned u[NC];
#pragma unroll
        for (int c = 0; c < NC; ++c)
            u[c] = *(const unsigned*)(kvc + base + (size_t)c * 4096);
        float r0 = 0.f, r1 = 0.f;
#pragma unroll
        for (int c = 0; c < NC; ++c) {
            const unsigned p = (unsigned)f2bf(r0) | ((unsigned)f2bf(r1) << 16);
            *(unsigned*)(spr + base + (size_t)c * 4096) = p;
            r0 += bf2f((us)(u[c] & 0xFFFF));
            r1 += bf2f((us)(u[c] >> 16));
        }
    } else if (tid < 64) {
        const size_t base = (size_t)(bh * NC) * 64 + tid;
        float zv[NC];
#pragma unroll
        for (int c = 0; c < NC; ++c) zv[c] = zc[base + (size_t)c * 64];
        float run = 0.f;
#pragma unroll
        for (int c = 0; c < NC; ++c) {
            zpr[base + (size_t)c * 64] = run;
            run += zv[c];
        }
    }
}

// ---------------------------------------------------------------------------
// chunk_attn: LDS-staged QK^T -> mask -> fused num/den MFMA pass.
// den = rowsum(A) + Q.z via virtual ones/z B-columns (R4-verified trick);
// only 2 barriers total.
// ---------------------------------------------------------------------------
__global__ __launch_bounds__(256) void chunk_attn(
    const us* __restrict__ qn, const us* __restrict__ kn,
    const us* __restrict__ vt, const us* __restrict__ spr,
    const float* __restrict__ zpr, us* __restrict__ attn)
{
    const int blk = blockIdx.x, bh = blk >> 5, c = blk & 31;
    const int t0 = c * CHUNK;
    __shared__ us Qs[4096], Kns[4096], Vts[4096], Sts[4096], Abf[4096];
    __shared__ float zp[64];
    const int tid = threadIdx.x;

    const us* qb = qn + ((size_t)bh * TT + t0) * HD;
    const us* kb = kn + ((size_t)bh * TT + t0) * HD;
    const us* vb = vt + (size_t)bh * HD * TT;
    const us* sb = spr + (size_t)blk * 4096;

#pragma unroll
    for (int i = 0; i < 2; ++i) {
        const int f = tid * 8 + i * 2048, row = f >> 6, kp = f & 63;
        const int kl = SWZ(row, kp);
        gload16(qb + (size_t)row * HD + kl, Qs + f);
        gload16(kb + (size_t)row * HD + kl, Kns + f);
        gload16(vb + (size_t)row * TT + t0 + kl, Vts + f);
        gload16(sb + (size_t)row * 64 + kl, Sts + f);
    }
    if (tid < 64) zp[tid] = zpr[(size_t)blk * 64 + tid];
    __syncthreads();

    const int lane = tid & 63, wid = tid >> 6;
    const int wr = wid >> 1, wc = wid & 1;
    const int lrow = lane & 15, lk8 = (lane >> 4) * 8, lr4 = (lane >> 4) * 4;

    // QK^T
    f32x4 accs[2][2] = {};
#pragma unroll
    for (int kin = 0; kin < 64; kin += 32) {
        bf16x8 af[2], bfr[2];
#pragma unroll
        for (int mi = 0; mi < 2; ++mi) {
            const int row = wr * 32 + mi * 16 + lrow;
            af[mi] = *(const bf16x8*)&Qs[row * 64 + SWZ(row, kin + lk8)];
        }
#pragma unroll
        for (int ni = 0; ni < 2; ++ni) {
            const int row = wc * 32 + ni * 16 + lrow;
            bfr[ni] = *(const bf16x8*)&Kns[row * 64 + SWZ(row, kin + lk8)];
        }
#pragma unroll
        for (int mi = 0; mi < 2; ++mi)
#pragma unroll
            for (int ni = 0; ni < 2; ++ni)
                accs[mi][ni] = __builtin_amdgcn_mfma_f32_16x16x32_bf16(
                    af[mi], bfr[ni], accs[mi][ni], 0, 0, 0);
    }

    // mask + bf16 store of scores
#pragma unroll
    for (int mi = 0; mi < 2; ++mi)
#pragma unroll
        for (int ni = 0; ni < 2; ++ni) {
            const int j = wc * 32 + ni * 16 + lrow;
#pragma unroll
            for (int r = 0; r < 4; ++r) {
                const int i = wr * 32 + mi * 16 + lr4 + r;
                const float v = (j <= i) ? accs[mi][ni][r] : 0.f;
                Abf[i * 64 + SWZ(i, j)] = f2bf(v);
            }
        }
    __syncthreads();

    // virtual B columns for den
    bf16x8 onesB = {}, zB = {};
    if (lrow == 0) {
#pragma unroll
        for (int e = 0; e < 8; ++e) {
            onesB[e] = (short)0x3F80;
            zB[e] = (short)f2bf(zp[lk8 + e]);
        }
    }

    // num = A@V + Q@S ; den = A@ones + Q@z
    f32x4 acco[2][2] = {};
    f32x4 accd[2] = {};
#pragma unroll
    for (int kin = 0; kin < 64; kin += 32) {
        bf16x8 af_a[2], af_q[2], bfr[2], bgr[2];
#pragma unroll
        for (int mi = 0; mi < 2; ++mi) {
            const int row = wr * 32 + mi * 16 + lrow;
            af_a[mi] = *(const bf16x8*)&Abf[row * 64 + SWZ(row, kin + lk8)];
            af_q[mi] = *(const bf16x8*)&Qs[row * 64 + SWZ(row, kin + lk8)];
        }
#pragma unroll
        for (int ni = 0; ni < 2; ++ni) {
            const int row = wc * 32 + ni * 16 + lrow;
            bfr[ni] = *(const bf16x8*)&Vts[row * 64 + SWZ(row, kin + lk8)];
            bgr[ni] = *(const bf16x8*)&Sts[row * 64 + SWZ(row, kin + lk8)];
        }
#pragma unroll
        for (int mi = 0; mi < 2; ++mi) {
            accd[mi] = __builtin_amdgcn_mfma_f32_16x16x32_bf16(
                af_a[mi], onesB, accd[mi], 0, 0, 0);
            accd[mi] = __builtin_amdgcn_mfma_f32_16x16x32_bf16(
                af_q[mi], zB, accd[mi], 0, 0, 0);
#pragma unroll
            for (int ni = 0; ni < 2; ++ni) {
                acco[mi][ni] = __builtin_amdgcn_mfma_f32_16x16x32_bf16(
                    af_a[mi], bfr[ni], acco[mi][ni], 0, 0, 0);
                acco[mi][ni] = __builtin_amdgcn_mfma_f32_16x16x32_bf16(
                    af_q[mi], bgr[ni], acco[mi][ni], 0, 0, 0);
            }
        }
    }

    // den lives in col-0 lanes (lane & 48); broadcast within 16-lane groups
    float denr[2][4];
#pragma unroll
    for (int mi = 0; mi < 2; ++mi)
#pragma unroll
        for (int r = 0; r < 4; ++r)
            denr[mi][r] = fmaxf(__shfl(accd[mi][r], (int)(lane & 48), 64), EPSV);

    const int b = bh >> 3, h = bh & 7;
#pragma unroll
    for (int mi = 0; mi < 2; ++mi)
#pragma unroll
        for (int ni = 0; ni < 2; ++ni) {
            const int d2 = wc * 32 + ni * 16 + lrow;
#pragma unroll
            for (int r = 0; r < 4; ++r) {
                const int i = wr * 32 + mi * 16 + lr4 + r;
                attn[((size_t)b * TT + t0 + i) * DM + h * HD + d2] =
                    f2bf(acco[mi][ni][r] / denr[mi][r]);
            }
        }
}

// ---------------------------------------------------------------------------
extern "C" void kernel_launch(void* const* d_in, const int* in_sizes, int n_in,
                              void* d_out, int out_size, void* d_ws, size_t ws_size,
                              hipStream_t stream)
{
    const float* x  = (const float*)d_in[0];
    const float* Wq = (const float*)d_in[1];
    const float* bq = (const float*)d_in[2];
    const float* Wk = (const float*)d_in[3];
    const float* bk = (const float*)d_in[4];
    const float* Wv = (const float*)d_in[5];
    const float* bv = (const float*)d_in[6];
    const float* Wo = (const float*)d_in[7];
    const float* bo = (const float*)d_in[8];
    float* out = (float*)d_out;

    const size_t SZ = (size_t)BH * TT * HD;        // 2,097,152 elems
    us* xb  = (us*)d_ws;                            // aliased as attn later
    us* WT  = xb + SZ;
    us* qn  = WT + (size_t)4 * DM * DM;
    us* kn  = qn + SZ;
    us* kt  = kn + SZ;
    us* vt  = kt + SZ;
    us* kvc = vt + SZ;
    us* spr = kvc + SZ;
    float* zc  = (float*)(spr + SZ);
    float* zpr = zc + (size_t)BH * NC * 64;
    us* attn = xb;

    prep<<<3072, 256, 0, stream>>>(x, Wq, Wk, Wv, Wo, xb, WT);
    qkv_mfma<<<dim3(ROWS / 128, DM / 128, 3), 256, 0, stream>>>(
        xb, WT, bq, bk, bv, qn, kn, kt, vt);
    chunk_sums<<<BH * NC, 256, 0, stream>>>(kt, vt, kvc, zc);
    scan<<<dim3(BH, 9), 256, 0, stream>>>(kvc, zc, spr, zpr);
    chunk_attn<<<BH * NC, 256, 0, stream>>>(qn, kn, vt, spr, zpr, attn);
    out_mfma<<<dim3(ROWS / 128, DM / 128), 256, 0, stream>>>(
        attn, WT + (size_t)3 * DM * DM, bo, out);
}

// Round 7
// 52.635 us; speedup vs baseline: 1.0076x; 1.0076x over previous
//
#include <hip/hip_runtime.h>
#include <math.h>

#define DM 512
#define NH 8
#define HD 64
#define BB 2
#define TT 2048
#define CHUNK 64
#define NC (TT / CHUNK)   /* 32 */
#define BH (BB * NH)      /* 16 */
#define ROWS (BB * TT)    /* 4096 */
#define EPSV 1e-6f

typedef short bf16x8 __attribute__((ext_vector_type(8)));
typedef float f32x4 __attribute__((ext_vector_type(4)));
typedef unsigned short us;

union U4 { us h[4]; uint2 u; };
union U8 { us h[8]; uint4 u; };

__device__ __forceinline__ us f2bf(float f) {
    unsigned int u = __float_as_uint(f);
    return (us)((u + 0x7FFFu + ((u >> 16) & 1u)) >> 16);
}
__device__ __forceinline__ float bf2f(us h) {
    return __uint_as_float(((unsigned int)h) << 16);
}
__device__ __forceinline__ void gload16(const void* g, void* l) {
    __builtin_amdgcn_global_load_lds(
        (const __attribute__((address_space(1))) unsigned int*)g,
        (__attribute__((address_space(3))) unsigned int*)l, 16, 0, 0);
}
// XOR swizzle on 16B blocks within a 64-elem bf16 row.
#define SWZ(r, k) ((k) ^ (((r) & 7) << 3))

// ---------------------------------------------------------------------------
// prepW: W (512x512 f32 [k][n]) -> WT (bf16 [n][k]), 4 weights, 1024 blocks.
// ---------------------------------------------------------------------------
__global__ __launch_bounds__(256) void prepW(
    const float* __restrict__ Wq, const float* __restrict__ Wk,
    const float* __restrict__ Wv, const float* __restrict__ Wo,
    us* __restrict__ WT)
{
    const int bid = blockIdx.x, tid = threadIdx.x;
    const int which = bid >> 8, t = bid & 255;
    const float* W = (which == 0) ? Wq : (which == 1) ? Wk : (which == 2) ? Wv : Wo;
    us* O = WT + (size_t)which * DM * DM;

    __shared__ float tl[32][33];
    const int r0 = (t >> 4) * 32, c0 = (t & 15) * 32;
    const int tr = tid >> 3, tc = tid & 7;
    float4 v = *(const float4*)&W[(size_t)(r0 + tr) * DM + c0 + tc * 4];
    tl[tr][tc * 4 + 0] = v.x; tl[tr][tc * 4 + 1] = v.y;
    tl[tr][tc * 4 + 2] = v.z; tl[tr][tc * 4 + 3] = v.w;
    __syncthreads();
    U4 o;
#pragma unroll
    for (int i = 0; i < 4; ++i) o.h[i] = f2bf(tl[tc * 4 + i][tr]);
    *(uint2*)&O[(size_t)(c0 + tr) * DM + r0 + tc * 4] = o.u;
}

// ---------------------------------------------------------------------------
// QKV projection: C = x @ W (+bias,+phi).  A-tile reg-staged from f32 x
// (cvt->ds_write_b128); B-tile gload16 from pre-transposed bf16 WT.
// 64x128 tile, BK=64, single-buffered (R3-verified shape).
// Q natural; K natural + transposed; V transposed.
// ---------------------------------------------------------------------------
__global__ __launch_bounds__(256) void qkv_mfma(
    const float* __restrict__ x, const us* __restrict__ WT,
    const float* __restrict__ bq, const float* __restrict__ bk,
    const float* __restrict__ bv,
    us* __restrict__ qn, us* __restrict__ kn,
    us* __restrict__ kt, us* __restrict__ vt)
{
    const int which = blockIdx.z;
    const us* Bg = WT + (size_t)which * DM * DM;
    const float* bias = (which == 0) ? bq : (which == 1) ? bk : bv;

    __shared__ us Asl[4096];
    __shared__ us Bsl[8192];

    f32x4 acc[2][4] = {};
    const int r0 = blockIdx.x * 64, c0 = blockIdx.y * 128;
    const int tid = threadIdx.x;
    const int lane = tid & 63, wid = tid >> 6;
    const int wr = wid >> 1, wc = wid & 1;
    const int lrow = lane & 15, lk8 = (lane >> 4) * 8;
    const int fa = tid * 8;

    for (int k0 = 0; k0 < DM; k0 += 64) {
        __syncthreads();
        // A: reg-stage + convert from f32 x (coalesced float4 pairs)
#pragma unroll
        for (int i = 0; i < 2; ++i) {
            const int f = fa + i * 2048, row = f >> 6, kp = f & 63;
            const float4 xa = *(const float4*)&x[(size_t)(r0 + row) * DM + k0 + kp];
            const float4 xc = *(const float4*)&x[(size_t)(r0 + row) * DM + k0 + kp + 4];
            U8 p;
            p.h[0] = f2bf(xa.x); p.h[1] = f2bf(xa.y);
            p.h[2] = f2bf(xa.z); p.h[3] = f2bf(xa.w);
            p.h[4] = f2bf(xc.x); p.h[5] = f2bf(xc.y);
            p.h[6] = f2bf(xc.z); p.h[7] = f2bf(xc.w);
            *(uint4*)&Asl[row * 64 + SWZ(row, kp)] = p.u;
        }
        // B: async global->LDS (pre-swizzled source)
#pragma unroll
        for (int i = 0; i < 4; ++i) {
            const int f = fa + i * 2048, row = f >> 6, kp = f & 63;
            gload16(Bg + (size_t)(c0 + row) * DM + k0 + SWZ(row, kp), Bsl + f);
        }
        __syncthreads();
#pragma unroll
        for (int kin = 0; kin < 64; kin += 32) {
            bf16x8 af[2], bfr[4];
#pragma unroll
            for (int mi = 0; mi < 2; ++mi) {
                const int row = wr * 32 + mi * 16 + lrow;
                af[mi] = *(const bf16x8*)&Asl[row * 64 + SWZ(row, kin + lk8)];
            }
#pragma unroll
            for (int ni = 0; ni < 4; ++ni) {
                const int row = wc * 64 + ni * 16 + lrow;
                bfr[ni] = *(const bf16x8*)&Bsl[row * 64 + SWZ(row, kin + lk8)];
            }
#pragma unroll
            for (int mi = 0; mi < 2; ++mi)
#pragma unroll
                for (int ni = 0; ni < 4; ++ni)
                    acc[mi][ni] = __builtin_amdgcn_mfma_f32_16x16x32_bf16(
                        af[mi], bfr[ni], acc[mi][ni], 0, 0, 0);
        }
    }

    const int lr4 = (lane >> 4) * 4;
    const int b = r0 >> 11;

#pragma unroll
    for (int mi = 0; mi < 2; ++mi) {
        const int rowb = r0 + wr * 32 + mi * 16 + lr4;
        const int t0g = rowb & (TT - 1);
#pragma unroll
        for (int ni = 0; ni < 4; ++ni) {
            const int col = c0 + wc * 64 + ni * 16 + lrow;
            const int h = col >> 6, d = col & 63;
            const float bc = bias[col];
            U4 p4;
#pragma unroll
            for (int r = 0; r < 4; ++r) {
                float y = acc[mi][ni][r] + bc;
                if (which < 2) y = (y > 0.f) ? (y + 1.f) : __expf(y);
                const us hb = f2bf(y);
                p4.h[r] = hb;
                if (which == 0)
                    qn[((size_t)(b * NH + h) * TT + t0g + r) * HD + d] = hb;
                else if (which == 1)
                    kn[((size_t)(b * NH + h) * TT + t0g + r) * HD + d] = hb;
            }
            if (which == 1)
                *(uint2*)&kt[((size_t)(b * NH + h) * HD + d) * TT + t0g] = p4.u;
            else if (which == 2)
                *(uint2*)&vt[((size_t)(b * NH + h) * HD + d) * TT + t0g] = p4.u;
        }
    }
}

// ---------------------------------------------------------------------------
// Output projection: out = attn(bf16) @ Wo^T + bo, f32 out (64x128 tile).
// ---------------------------------------------------------------------------
__global__ __launch_bounds__(256) void out_mfma(
    const us* __restrict__ Ag, const us* __restrict__ WoT,
    const float* __restrict__ bias, float* __restrict__ out)
{
    __shared__ us Asl[4096];
    __shared__ us Bsl[8192];
    f32x4 acc[2][4] = {};
    const int r0 = blockIdx.x * 64, c0 = blockIdx.y * 128;
    const int tid = threadIdx.x;
    const int lane = tid & 63, wid = tid >> 6;
    const int wr = wid >> 1, wc = wid & 1;
    const int lrow = lane & 15, lk8 = (lane >> 4) * 8;
    const int fa = tid * 8;

    for (int k0 = 0; k0 < DM; k0 += 64) {
        __syncthreads();
#pragma unroll
        for (int i = 0; i < 2; ++i) {
            const int f = fa + i * 2048, row = f >> 6, kp = f & 63;
            gload16(Ag + (size_t)(r0 + row) * DM + k0 + SWZ(row, kp), Asl + f);
        }
#pragma unroll
        for (int i = 0; i < 4; ++i) {
            const int f = fa + i * 2048, row = f >> 6, kp = f & 63;
            gload16(WoT + (size_t)(c0 + row) * DM + k0 + SWZ(row, kp), Bsl + f);
        }
        __syncthreads();
#pragma unroll
        for (int kin = 0; kin < 64; kin += 32) {
            bf16x8 af[2], bfr[4];
#pragma unroll
            for (int mi = 0; mi < 2; ++mi) {
                const int row = wr * 32 + mi * 16 + lrow;
                af[mi] = *(const bf16x8*)&Asl[row * 64 + SWZ(row, kin + lk8)];
            }
#pragma unroll
            for (int ni = 0; ni < 4; ++ni) {
                const int row = wc * 64 + ni * 16 + lrow;
                bfr[ni] = *(const bf16x8*)&Bsl[row * 64 + SWZ(row, kin + lk8)];
            }
#pragma unroll
            for (int mi = 0; mi < 2; ++mi)
#pragma unroll
                for (int ni = 0; ni < 4; ++ni)
                    acc[mi][ni] = __builtin_amdgcn_mfma_f32_16x16x32_bf16(
                        af[mi], bfr[ni], acc[mi][ni], 0, 0, 0);
        }
    }

    const int lr4 = (lane >> 4) * 4;
#pragma unroll
    for (int mi = 0; mi < 2; ++mi)
#pragma unroll
        for (int ni = 0; ni < 4; ++ni) {
            const int col = c0 + wc * 64 + ni * 16 + lrow;
            const float bc = bias[col];
#pragma unroll
            for (int r = 0; r < 4; ++r) {
                const int row = r0 + wr * 32 + mi * 16 + lr4 + r;
                out[(size_t)row * DM + col] = acc[mi][ni][r] + bc;
            }
        }
}

// ---------------------------------------------------------------------------
// sums_seg: grid (bh*8).  Each block walks 4 chunks serially, MFMA-
// accumulating KV^T and z in C-registers; writes the EXCLUSIVE local prefix
// per chunk (spr, zloc) and the segment total (segsum, zseg).
// Replaces chunk_sums + scan; kvc buffer eliminated.
// ---------------------------------------------------------------------------
__global__ __launch_bounds__(256) void sums_seg(
    const us* __restrict__ kt, const us* __restrict__ vt,
    us* __restrict__ spr, us* __restrict__ segsum,
    float* __restrict__ zloc, float* __restrict__ zseg)
{
    const int bid = blockIdx.x;           // 0..127
    const int bh = bid >> 3, seg = bid & 7;
    __shared__ us Ksl[4096], Vsl[4096];
    const int tid = threadIdx.x, lane = tid & 63, wid = tid >> 6;
    const int wr = wid >> 1, wc = wid & 1;
    const int lrow = lane & 15, lk8 = (lane >> 4) * 8, lr4 = (lane >> 4) * 4;
    const us* ktb = kt + (size_t)bh * HD * TT;
    const us* vtb = vt + (size_t)bh * HD * TT;

    bf16x8 onesA = {};
    if (lrow == 0)
#pragma unroll
        for (int e = 0; e < 8; ++e) onesA[e] = (short)0x3F80;

    f32x4 run[2][2] = {};
    f32x4 runz[2] = {};

    for (int cc = 0; cc < 4; ++cc) {
        const int c = seg * 4 + cc, t0 = c * CHUNK;
        __syncthreads();                  // protect LDS from prior reads
#pragma unroll
        for (int i = 0; i < 2; ++i) {
            const int f = tid * 8 + i * 2048, row = f >> 6, kp = f & 63;
            const int kl = SWZ(row, kp);
            gload16(ktb + (size_t)row * TT + t0 + kl, Ksl + f);
            gload16(vtb + (size_t)row * TT + t0 + kl, Vsl + f);
        }
        // write exclusive prefix (run BEFORE this chunk) while loads fly
        us* dst = spr + (size_t)(bh * NC + c) * 4096;
#pragma unroll
        for (int mi = 0; mi < 2; ++mi)
#pragma unroll
            for (int ni = 0; ni < 2; ++ni) {
                const int d2 = wr * 32 + mi * 16 + lr4;
                const int d1 = wc * 32 + ni * 16 + lrow;
#pragma unroll
                for (int r = 0; r < 4; ++r)
                    dst[(d2 + r) * 64 + d1] = f2bf(run[mi][ni][r]);
            }
        if (wr == 0 && lane < 16)
#pragma unroll
            for (int ni = 0; ni < 2; ++ni)
                zloc[(size_t)(bh * NC + c) * 64 + wc * 32 + ni * 16 + lane] = runz[ni][0];
        __syncthreads();
        // accumulate chunk into run (MFMA C-in/C-out)
#pragma unroll
        for (int kin = 0; kin < 64; kin += 32) {
            bf16x8 af[2], bfr[2];
#pragma unroll
            for (int mi = 0; mi < 2; ++mi) {
                const int row = wr * 32 + mi * 16 + lrow;
                af[mi] = *(const bf16x8*)&Vsl[row * 64 + SWZ(row, kin + lk8)];
            }
#pragma unroll
            for (int ni = 0; ni < 2; ++ni) {
                const int row = wc * 32 + ni * 16 + lrow;
                bfr[ni] = *(const bf16x8*)&Ksl[row * 64 + SWZ(row, kin + lk8)];
            }
#pragma unroll
            for (int mi = 0; mi < 2; ++mi)
#pragma unroll
                for (int ni = 0; ni < 2; ++ni)
                    run[mi][ni] = __builtin_amdgcn_mfma_f32_16x16x32_bf16(
                        af[mi], bfr[ni], run[mi][ni], 0, 0, 0);
            if (wr == 0)
#pragma unroll
                for (int ni = 0; ni < 2; ++ni)
                    runz[ni] = __builtin_amdgcn_mfma_f32_16x16x32_bf16(
                        onesA, bfr[ni], runz[ni], 0, 0, 0);
        }
    }

    // segment totals
    us* sdst = segsum + (size_t)(bh * 8 + seg) * 4096;
#pragma unroll
    for (int mi = 0; mi < 2; ++mi)
#pragma unroll
        for (int ni = 0; ni < 2; ++ni) {
            const int d2 = wr * 32 + mi * 16 + lr4;
            const int d1 = wc * 32 + ni * 16 + lrow;
#pragma unroll
            for (int r = 0; r < 4; ++r)
                sdst[(d2 + r) * 64 + d1] = f2bf(run[mi][ni][r]);
        }
    if (wr == 0 && lane < 16)
#pragma unroll
        for (int ni = 0; ni < 2; ++ni)
            zseg[(size_t)(bh * 8 + seg) * 64 + wc * 32 + ni * 16 + lane] = runz[ni][0];
}

// ---------------------------------------------------------------------------
// chunk_attn: Sts/zp reg-staged as local-prefix + sum of segment totals;
// QK^T -> mask -> fused num/den MFMA pass (virtual ones/z B-columns).
// ---------------------------------------------------------------------------
__global__ __launch_bounds__(256) void chunk_attn(
    const us* __restrict__ qn, const us* __restrict__ kn,
    const us* __restrict__ vt, const us* __restrict__ spr,
    const us* __restrict__ segsum, const float* __restrict__ zloc,
    const float* __restrict__ zseg, us* __restrict__ attn)
{
    const int blk = blockIdx.x, bh = blk >> 5, c = blk & 31;
    const int t0 = c * CHUNK, seg = c >> 2;
    __shared__ us Qs[4096], Kns[4096], Vts[4096], Sts[4096], Abf[4096];
    __shared__ float zp[64];
    const int tid = threadIdx.x;

    const us* qb = qn + ((size_t)bh * TT + t0) * HD;
    const us* kb = kn + ((size_t)bh * TT + t0) * HD;
    const us* vb = vt + (size_t)bh * HD * TT;
    const us* sprL = spr + (size_t)blk * 4096;
    const us* segb = segsum + (size_t)(bh * 8) * 4096;

#pragma unroll
    for (int i = 0; i < 2; ++i) {
        const int f = tid * 8 + i * 2048, row = f >> 6, kp = f & 63;
        const int kl = SWZ(row, kp);
        gload16(qb + (size_t)row * HD + kl, Qs + f);
        gload16(kb + (size_t)row * HD + kl, Kns + f);
        gload16(vb + (size_t)row * TT + t0 + kl, Vts + f);
    }
    // Sts = local prefix + sum of previous segment totals (reg-staged)
#pragma unroll
    for (int i = 0; i < 2; ++i) {
        const int f = tid * 8 + i * 2048, row = f >> 6, kp = f & 63;
        float sacc[8];
        const bf16x8 v0 = *(const bf16x8*)&sprL[row * 64 + kp];
#pragma unroll
        for (int e = 0; e < 8; ++e) sacc[e] = bf2f((us)v0[e]);
        for (int s = 0; s < seg; ++s) {
            const bf16x8 vs = *(const bf16x8*)&segb[(size_t)s * 4096 + row * 64 + kp];
#pragma unroll
            for (int e = 0; e < 8; ++e) sacc[e] += bf2f((us)vs[e]);
        }
        U8 p;
#pragma unroll
        for (int e = 0; e < 8; ++e) p.h[e] = f2bf(sacc[e]);
        *(uint4*)&Sts[row * 64 + SWZ(row, kp)] = p.u;
    }
    if (tid < 64) {
        float zv = zloc[(size_t)blk * 64 + tid];
        for (int s = 0; s < seg; ++s) zv += zseg[(size_t)(bh * 8 + s) * 64 + tid];
        zp[tid] = zv;
    }
    __syncthreads();

    const int lane = tid & 63, wid = tid >> 6;
    const int wr = wid >> 1, wc = wid & 1;
    const int lrow = lane & 15, lk8 = (lane >> 4) * 8, lr4 = (lane >> 4) * 4;

    // QK^T
    f32x4 accs[2][2] = {};
#pragma unroll
    for (int kin = 0; kin < 64; kin += 32) {
        bf16x8 af[2], bfr[2];
#pragma unroll
        for (int mi = 0; mi < 2; ++mi) {
            const int row = wr * 32 + mi * 16 + lrow;
            af[mi] = *(const bf16x8*)&Qs[row * 64 + SWZ(row, kin + lk8)];
        }
#pragma unroll
        for (int ni = 0; ni < 2; ++ni) {
            const int row = wc * 32 + ni * 16 + lrow;
            bfr[ni] = *(const bf16x8*)&Kns[row * 64 + SWZ(row, kin + lk8)];
        }
#pragma unroll
        for (int mi = 0; mi < 2; ++mi)
#pragma unroll
            for (int ni = 0; ni < 2; ++ni)
                accs[mi][ni] = __builtin_amdgcn_mfma_f32_16x16x32_bf16(
                    af[mi], bfr[ni], accs[mi][ni], 0, 0, 0);
    }

    // mask + bf16 store of scores
#pragma unroll
    for (int mi = 0; mi < 2; ++mi)
#pragma unroll
        for (int ni = 0; ni < 2; ++ni) {
            const int j = wc * 32 + ni * 16 + lrow;
#pragma unroll
            for (int r = 0; r < 4; ++r) {
                const int i = wr * 32 + mi * 16 + lr4 + r;
                const float v = (j <= i) ? accs[mi][ni][r] : 0.f;
                Abf[i * 64 + SWZ(i, j)] = f2bf(v);
            }
        }
    __syncthreads();

    // virtual B columns for den
    bf16x8 onesB = {}, zB = {};
    if (lrow == 0) {
#pragma unroll
        for (int e = 0; e < 8; ++e) {
            onesB[e] = (short)0x3F80;
            zB[e] = (short)f2bf(zp[lk8 + e]);
        }
    }

    // num = A@V + Q@S ; den = A@ones + Q@z
    f32x4 acco[2][2] = {};
    f32x4 accd[2] = {};
#pragma unroll
    for (int kin = 0; kin < 64; kin += 32) {
        bf16x8 af_a[2], af_q[2], bfr[2], bgr[2];
#pragma unroll
        for (int mi = 0; mi < 2; ++mi) {
            const int row = wr * 32 + mi * 16 + lrow;
            af_a[mi] = *(const bf16x8*)&Abf[row * 64 + SWZ(row, kin + lk8)];
            af_q[mi] = *(const bf16x8*)&Qs[row * 64 + SWZ(row, kin + lk8)];
        }
#pragma unroll
        for (int ni = 0; ni < 2; ++ni) {
            const int row = wc * 32 + ni * 16 + lrow;
            bfr[ni] = *(const bf16x8*)&Vts[row * 64 + SWZ(row, kin + lk8)];
            bgr[ni] = *(const bf16x8*)&Sts[row * 64 + SWZ(row, kin + lk8)];
        }
#pragma unroll
        for (int mi = 0; mi < 2; ++mi) {
            accd[mi] = __builtin_amdgcn_mfma_f32_16x16x32_bf16(
                af_a[mi], onesB, accd[mi], 0, 0, 0);
            accd[mi] = __builtin_amdgcn_mfma_f32_16x16x32_bf16(
                af_q[mi], zB, accd[mi], 0, 0, 0);
#pragma unroll
            for (int ni = 0; ni < 2; ++ni) {
                acco[mi][ni] = __builtin_amdgcn_mfma_f32_16x16x32_bf16(
                    af_a[mi], bfr[ni], acco[mi][ni], 0, 0, 0);
                acco[mi][ni] = __builtin_amdgcn_mfma_f32_16x16x32_bf16(
                    af_q[mi], bgr[ni], acco[mi][ni], 0, 0, 0);
            }
        }
    }

    // den broadcast within 16-lane groups (col-0 lanes hold it)
    float denr[2][4];
#pragma unroll
    for (int mi = 0; mi < 2; ++mi)
#pragma unroll
        for (int r = 0; r < 4; ++r)
            denr[mi][r] = fmaxf(__shfl(accd[mi][r], (int)(lane & 48), 64), EPSV);

    const int b = bh >> 3, h = bh & 7;
#pragma unroll
    for (int mi = 0; mi < 2; ++mi)
#pragma unroll
        for (int ni = 0; ni < 2; ++ni) {
            const int d2 = wc * 32 + ni * 16 + lrow;
#pragma unroll
            for (int r = 0; r < 4; ++r) {
                const int i = wr * 32 + mi * 16 + lr4 + r;
                attn[((size_t)b * TT + t0 + i) * DM + h * HD + d2] =
                    f2bf(acco[mi][ni][r] / denr[mi][r]);
            }
        }
}

// ---------------------------------------------------------------------------
extern "C" void kernel_launch(void* const* d_in, const int* in_sizes, int n_in,
                              void* d_out, int out_size, void* d_ws, size_t ws_size,
                              hipStream_t stream)
{
    const float* x  = (const float*)d_in[0];
    const float* Wq = (const float*)d_in[1];
    const float* bq = (const float*)d_in[2];
    const float* Wk = (const float*)d_in[3];
    const float* bk = (const float*)d_in[4];
    const float* Wv = (const float*)d_in[5];
    const float* bv = (const float*)d_in[6];
    const float* Wo = (const float*)d_in[7];
    const float* bo = (const float*)d_in[8];
    float* out = (float*)d_out;

    const size_t SZ = (size_t)BH * TT * HD;        // 2,097,152 elems
    us* WT   = (us*)d_ws;                           // 4 transposed weights
    us* qn   = WT + (size_t)4 * DM * DM;
    us* kn   = qn + SZ;
    us* kt   = kn + SZ;
    us* vt   = kt + SZ;
    us* spr  = vt + SZ;                             // exclusive local prefixes
    us* segsum = spr + SZ;                          // 16*8*4096
    us* attn = segsum + (size_t)BH * 8 * 4096;
    float* zloc = (float*)(attn + SZ);              // BH*NC*64
    float* zseg = zloc + (size_t)BH * NC * 64;      // BH*8*64

    prepW<<<1024, 256, 0, stream>>>(Wq, Wk, Wv, Wo, WT);
    qkv_mfma<<<dim3(ROWS / 64, DM / 128, 3), 256, 0, stream>>>(
        x, WT, bq, bk, bv, qn, kn, kt, vt);
    sums_seg<<<BH * 8, 256, 0, stream>>>(kt, vt, spr, segsum, zloc, zseg);
    chunk_attn<<<BH * NC, 256, 0, stream>>>(qn, kn, vt, spr, segsum, zloc, zseg, attn);
    out_mfma<<<dim3(ROWS / 64, DM / 128), 256, 0, stream>>>(
        attn, WT + (size_t)3 * DM * DM, bo, out);
}

// Round 8
// 46.181 us; speedup vs baseline: 1.1484x; 1.1397x over previous
//
#include <hip/hip_runtime.h>
#include <math.h>

#define DM 512
#define NH 8
#define HD 64
#define BB 2
#define TT 2048
#define CHUNK 64
#define NC (TT / CHUNK)   /* 32 */
#define BH (BB * NH)      /* 16 */
#define ROWS (BB * TT)    /* 4096 */
#define EPSV 1e-6f

typedef short bf16x8 __attribute__((ext_vector_type(8)));
typedef float f32x4 __attribute__((ext_vector_type(4)));
typedef unsigned short us;

union U4 { us h[4]; uint2 u; };

__device__ __forceinline__ us f2bf(float f) {
    unsigned int u = __float_as_uint(f);
    return (us)((u + 0x7FFFu + ((u >> 16) & 1u)) >> 16);
}
__device__ __forceinline__ float bf2f(us h) {
    return __uint_as_float(((unsigned int)h) << 16);
}
__device__ __forceinline__ void gload16(const void* g, void* l) {
    __builtin_amdgcn_global_load_lds(
        (const __attribute__((address_space(1))) unsigned int*)g,
        (__attribute__((address_space(3))) unsigned int*)l, 16, 0, 0);
}
// XOR swizzle on 16B blocks within a 64-elem bf16 row.
#define SWZ(r, k) ((k) ^ (((r) & 7) << 3))

// ---------------------------------------------------------------------------
// prep: blocks [0,2048): x f32 -> xb bf16.  blocks [2048,3072): W -> W^T bf16.
// ---------------------------------------------------------------------------
__global__ __launch_bounds__(256) void prep(
    const float* __restrict__ x,
    const float* __restrict__ Wq, const float* __restrict__ Wk,
    const float* __restrict__ Wv, const float* __restrict__ Wo,
    us* __restrict__ xb, us* __restrict__ WT)
{
    const int bid = blockIdx.x, tid = threadIdx.x;
    __shared__ float tl[32][33];
    if (bid < 2048) {
        const int i = bid * 256 + tid;
        float4 v = ((const float4*)x)[i];
        U4 o;
        o.h[0] = f2bf(v.x); o.h[1] = f2bf(v.y);
        o.h[2] = f2bf(v.z); o.h[3] = f2bf(v.w);
        ((uint2*)xb)[i] = o.u;
    } else {
        const int b2 = bid - 2048;
        const int which = b2 >> 8, t = b2 & 255;
        const float* W = (which == 0) ? Wq : (which == 1) ? Wk : (which == 2) ? Wv : Wo;
        us* O = WT + (size_t)which * DM * DM;
        const int r0 = (t >> 4) * 32, c0 = (t & 15) * 32;
        const int tr = tid >> 3, tc = tid & 7;
        float4 v = *(const float4*)&W[(size_t)(r0 + tr) * DM + c0 + tc * 4];
        tl[tr][tc * 4 + 0] = v.x; tl[tr][tc * 4 + 1] = v.y;
        tl[tr][tc * 4 + 2] = v.z; tl[tr][tc * 4 + 3] = v.w;
        __syncthreads();
        U4 o;
#pragma unroll
        for (int i = 0; i < 4; ++i) o.h[i] = f2bf(tl[tc * 4 + i][tr]);
        *(uint2*)&O[(size_t)(c0 + tr) * DM + r0 + tc * 4] = o.u;
    }
}

// ---------------------------------------------------------------------------
// Double-buffered 64x128 GEMM core (bf16): C = A[64xDM] @ B[128xDM]^T.
// T3-min: STAGE(next) issued before compute, ONE barrier per K-step.
// ---------------------------------------------------------------------------
__device__ __forceinline__ void stage_tiles(
    const us* __restrict__ Ag, const us* __restrict__ Bg,
    int r0, int c0, int k0, int tid, us* As, us* Bs)
{
    const int fa = tid * 8;
#pragma unroll
    for (int i = 0; i < 2; ++i) {
        const int f = fa + i * 2048, row = f >> 6, kp = f & 63;
        gload16(Ag + (size_t)(r0 + row) * DM + k0 + SWZ(row, kp), As + f);
    }
#pragma unroll
    for (int i = 0; i < 4; ++i) {
        const int f = fa + i * 2048, row = f >> 6, kp = f & 63;
        gload16(Bg + (size_t)(c0 + row) * DM + k0 + SWZ(row, kp), Bs + f);
    }
}

__device__ __forceinline__ void gemm64x128(
    const us* __restrict__ Ag, const us* __restrict__ Bg,
    int r0, int c0, int tid, us* Asl, us* Bsl, f32x4 (&acc)[2][4])
{
    const int lane = tid & 63, wid = tid >> 6;
    const int wr = wid >> 1, wc = wid & 1;
    const int lrow = lane & 15, lk8 = (lane >> 4) * 8;

    stage_tiles(Ag, Bg, r0, c0, 0, tid, Asl, Bsl);
    __syncthreads();
    int cur = 0;
    for (int k0 = 0; k0 < DM; k0 += 64) {
        if (k0 + 64 < DM)
            stage_tiles(Ag, Bg, r0, c0, k0 + 64, tid,
                        Asl + (cur ^ 1) * 4096, Bsl + (cur ^ 1) * 8192);
        const us* As = Asl + cur * 4096;
        const us* Bs = Bsl + cur * 8192;
#pragma unroll
        for (int kin = 0; kin < 64; kin += 32) {
            bf16x8 af[2], bfr[4];
#pragma unroll
            for (int mi = 0; mi < 2; ++mi) {
                const int row = wr * 32 + mi * 16 + lrow;
                af[mi] = *(const bf16x8*)&As[row * 64 + SWZ(row, kin + lk8)];
            }
#pragma unroll
            for (int ni = 0; ni < 4; ++ni) {
                const int row = wc * 64 + ni * 16 + lrow;
                bfr[ni] = *(const bf16x8*)&Bs[row * 64 + SWZ(row, kin + lk8)];
            }
#pragma unroll
            for (int mi = 0; mi < 2; ++mi)
#pragma unroll
                for (int ni = 0; ni < 4; ++ni)
                    acc[mi][ni] = __builtin_amdgcn_mfma_f32_16x16x32_bf16(
                        af[mi], bfr[ni], acc[mi][ni], 0, 0, 0);
        }
        __syncthreads();
        cur ^= 1;
    }
}

// ---------------------------------------------------------------------------
// QKV projection: Q natural, K natural + transposed, V transposed.  phi Q,K.
// kt/vt stores go through a t-major LDS bounce (reusing the staging LDS) so
// each global store is a 128B-contiguous t-run (no 4KB-stride scatter).
// ---------------------------------------------------------------------------
__global__ __launch_bounds__(256) void qkv_mfma(
    const us* __restrict__ xb, const us* __restrict__ WT,
    const float* __restrict__ bq, const float* __restrict__ bk,
    const float* __restrict__ bv,
    us* __restrict__ qn, us* __restrict__ kn,
    us* __restrict__ kt, us* __restrict__ vt)
{
    const int which = blockIdx.z;
    const us* Bg = WT + (size_t)which * DM * DM;
    const float* bias = (which == 0) ? bq : (which == 1) ? bk : bv;

    __shared__ us sh[24576];           // dbuf staging (48KB); reused as Cb
    us* Asl = sh;
    us* Bsl = sh + 8192;

    f32x4 acc[2][4] = {};
    const int r0 = blockIdx.x * 64, c0 = blockIdx.y * 128;
    const int tid = threadIdx.x;

    gemm64x128(xb, Bg, r0, c0, tid, Asl, Bsl, acc);

    const int lane = tid & 63, wid = tid >> 6;
    const int wr = wid >> 1, wc = wid & 1;
    const int lrow = lane & 15, lr4 = (lane >> 4) * 4;
    const int b = r0 >> 11, t0b = r0 & (TT - 1);

    if (which == 0) {
#pragma unroll
        for (int mi = 0; mi < 2; ++mi) {
            const int t0g = t0b + wr * 32 + mi * 16 + lr4;
#pragma unroll
            for (int ni = 0; ni < 4; ++ni) {
                const int col = c0 + wc * 64 + ni * 16 + lrow;
                const int h = col >> 6, d = col & 63;
                const float bc = bias[col];
#pragma unroll
                for (int r = 0; r < 4; ++r) {
                    float y = acc[mi][ni][r] + bc;
                    y = (y > 0.f) ? (y + 1.f) : __expf(y);
                    qn[((size_t)(b * NH + h) * TT + t0g + r) * HD + d] = f2bf(y);
                }
            }
        }
        return;
    }

    // which 1/2: bounce C-tile t-major into LDS (gemm ended with barrier).
    us* Cb = sh;                       // [128 cols][72] stride-72, 18.4 KB
#pragma unroll
    for (int mi = 0; mi < 2; ++mi) {
        const int tL = wr * 32 + mi * 16 + lr4;
#pragma unroll
        for (int ni = 0; ni < 4; ++ni) {
            const int colL = wc * 64 + ni * 16 + lrow;
            const int col = c0 + colL;
            const float bc = bias[col];
            U4 p4;
#pragma unroll
            for (int r = 0; r < 4; ++r) {
                float y = acc[mi][ni][r] + bc;
                if (which == 1) y = (y > 0.f) ? (y + 1.f) : __expf(y);
                p4.h[r] = f2bf(y);
            }
            if (which == 1) {
                const int h = col >> 6, d = col & 63;
#pragma unroll
                for (int r = 0; r < 4; ++r)
                    kn[((size_t)(b * NH + h) * TT + t0b + tL + r) * HD + d] = p4.h[r];
            }
            *(uint2*)&Cb[colL * 72 + tL] = p4.u;
        }
    }
    __syncthreads();

    us* dst = (which == 1) ? kt : vt;
#pragma unroll
    for (int it = 0; it < 4; ++it) {
        const int colL = it * 32 + wid * 8 + (lane >> 3);
        const int tch = (lane & 7) * 8;
        const uint4 v = *(const uint4*)&Cb[colL * 72 + tch];
        const int col = c0 + colL, h = col >> 6, d = col & 63;
        *(uint4*)&dst[((size_t)(b * NH + h) * HD + d) * TT + t0b + tch] = v;
    }
}

// ---------------------------------------------------------------------------
// Output projection: out = attn(bf16) @ Wo^T + bo, f32 out.
// ---------------------------------------------------------------------------
__global__ __launch_bounds__(256) void out_mfma(
    const us* __restrict__ Ag, const us* __restrict__ WoT,
    const float* __restrict__ bias, float* __restrict__ out)
{
    __shared__ us Asl[2 * 4096];
    __shared__ us Bsl[2 * 8192];
    f32x4 acc[2][4] = {};
    const int r0 = blockIdx.x * 64, c0 = blockIdx.y * 128;
    const int tid = threadIdx.x;

    gemm64x128(Ag, WoT, r0, c0, tid, Asl, Bsl, acc);

    const int lane = tid & 63, wid = tid >> 6;
    const int wr = wid >> 1, wc = wid & 1;
    const int lrow = lane & 15, lr4 = (lane >> 4) * 4;

#pragma unroll
    for (int mi = 0; mi < 2; ++mi)
#pragma unroll
        for (int ni = 0; ni < 4; ++ni) {
            const int col = c0 + wc * 64 + ni * 16 + lrow;
            const float bc = bias[col];
#pragma unroll
            for (int r = 0; r < 4; ++r) {
                const int row = r0 + wr * 32 + mi * 16 + lr4 + r;
                out[(size_t)row * DM + col] = acc[mi][ni][r] + bc;
            }
        }
}

// ---------------------------------------------------------------------------
// chunk_sums (R3 form): LDS-staged, coalesced.  S^T_c[d2][d1] and z_c.
// ---------------------------------------------------------------------------
__global__ __launch_bounds__(256) void chunk_sums(
    const us* __restrict__ kt, const us* __restrict__ vt,
    us* __restrict__ kvc, float* __restrict__ zc)
{
    const int blk = blockIdx.x, bh = blk >> 5, c = blk & 31;
    const int t0 = c * CHUNK;
    __shared__ us Ksl[4096], Vsl[4096];
    __shared__ float partial[4][64];
    const int tid = threadIdx.x;
    const us* ktb = kt + (size_t)bh * HD * TT;
    const us* vtb = vt + (size_t)bh * HD * TT;

#pragma unroll
    for (int i = 0; i < 2; ++i) {
        const int f = tid * 8 + i * 2048, row = f >> 6, kp = f & 63;
        const int kl = SWZ(row, kp);
        gload16(ktb + (size_t)row * TT + t0 + kl, Ksl + f);
        gload16(vtb + (size_t)row * TT + t0 + kl, Vsl + f);
    }
    __syncthreads();

    const int lane = tid & 63, wid = tid >> 6;
    const int wr = wid >> 1, wc = wid & 1;
    const int lrow = lane & 15, lk8 = (lane >> 4) * 8, lr4 = (lane >> 4) * 4;

    f32x4 acc[2][2] = {};
#pragma unroll
    for (int kin = 0; kin < 64; kin += 32) {
        bf16x8 af[2], bfr[2];
#pragma unroll
        for (int mi = 0; mi < 2; ++mi) {
            const int row = wr * 32 + mi * 16 + lrow;
            af[mi] = *(const bf16x8*)&Vsl[row * 64 + SWZ(row, kin + lk8)];
        }
#pragma unroll
        for (int ni = 0; ni < 2; ++ni) {
            const int row = wc * 32 + ni * 16 + lrow;
            bfr[ni] = *(const bf16x8*)&Ksl[row * 64 + SWZ(row, kin + lk8)];
        }
#pragma unroll
        for (int mi = 0; mi < 2; ++mi)
#pragma unroll
            for (int ni = 0; ni < 2; ++ni)
                acc[mi][ni] = __builtin_amdgcn_mfma_f32_16x16x32_bf16(
                    af[mi], bfr[ni], acc[mi][ni], 0, 0, 0);
    }

    us* dst = kvc + (size_t)blk * 4096;
#pragma unroll
    for (int mi = 0; mi < 2; ++mi)
#pragma unroll
        for (int ni = 0; ni < 2; ++ni) {
            const int d2 = wr * 32 + mi * 16 + lr4;
            const int d1 = wc * 32 + ni * 16 + lrow;
#pragma unroll
            for (int r = 0; r < 4; ++r)
                dst[(d2 + r) * 64 + d1] = f2bf(acc[mi][ni][r]);
        }

    // z: row sums of K^T (logical [d][t])
    {
        const int p = tid >> 6, d = tid & 63;
        float s = 0.f;
#pragma unroll
        for (int j = 0; j < 16; ++j)
            s += bf2f(Ksl[d * 64 + SWZ(d, p * 16 + j)]);
        partial[p][d] = s;
    }
    __syncthreads();
    if (tid < 64)
        zc[(size_t)blk * 64 + tid] =
            partial[0][tid] + partial[1][tid] + partial[2][tid] + partial[3][tid];
}

// ---------------------------------------------------------------------------
// scan: exclusive prefix over chunks, register-blocked two-phase.
// ---------------------------------------------------------------------------
__global__ __launch_bounds__(256) void scan(
    const us* __restrict__ kvc, const float* __restrict__ zc,
    us* __restrict__ spr, float* __restrict__ zpr)
{
    const int bh = blockIdx.x, seg = blockIdx.y, tid = threadIdx.x;
    if (seg < 8) {
        const int e = seg * 512 + tid * 2;
        const size_t base = (size_t)(bh * NC) * 4096 + e;
        unsigned u[NC];
#pragma unroll
        for (int c = 0; c < NC; ++c)
            u[c] = *(const unsigned*)(kvc + base + (size_t)c * 4096);
        float r0 = 0.f, r1 = 0.f;
#pragma unroll
        for (int c = 0; c < NC; ++c) {
            const unsigned p = (unsigned)f2bf(r0) | ((unsigned)f2bf(r1) << 16);
            *(unsigned*)(spr + base + (size_t)c * 4096) = p;
            r0 += bf2f((us)(u[c] & 0xFFFF));
            r1 += bf2f((us)(u[c] >> 16));
        }
    } else if (tid < 64) {
        const size_t base = (size_t)(bh * NC) * 64 + tid;
        float zv[NC];
#pragma unroll
        for (int c = 0; c < NC; ++c) zv[c] = zc[base + (size_t)c * 64];
        float run = 0.f;
#pragma unroll
        for (int c = 0; c < NC; ++c) {
            zpr[base + (size_t)c * 64] = run;
            run += zv[c];
        }
    }
}

// ---------------------------------------------------------------------------
// chunk_attn (R3 form): LDS-staged, MFMA QK^T -> mask -> den -> MFMA
// (A@V + Q@S) -> /den -> bf16 attn (B,T,DM).
// ---------------------------------------------------------------------------
__global__ __launch_bounds__(256) void chunk_attn(
    const us* __restrict__ qn, const us* __restrict__ kn,
    const us* __restrict__ vt, const us* __restrict__ spr,
    const float* __restrict__ zpr, us* __restrict__ attn)
{
    const int blk = blockIdx.x, bh = blk >> 5, c = blk & 31;
    const int t0 = c * CHUNK;
    __shared__ us Qs[4096], Kns[4096], Vts[4096], Sts[4096], Abf[4096];
    __shared__ float zp[64], den[64], part[4][64];
    const int tid = threadIdx.x;

    const us* qb = qn + ((size_t)bh * TT + t0) * HD;
    const us* kb = kn + ((size_t)bh * TT + t0) * HD;
    const us* vb = vt + (size_t)bh * HD * TT;
    const us* sb = spr + (size_t)blk * 4096;

#pragma unroll
    for (int i = 0; i < 2; ++i) {
        const int f = tid * 8 + i * 2048, row = f >> 6, kp = f & 63;
        const int kl = SWZ(row, kp);
        gload16(qb + (size_t)row * HD + kl, Qs + f);
        gload16(kb + (size_t)row * HD + kl, Kns + f);
        gload16(vb + (size_t)row * TT + t0 + kl, Vts + f);
        gload16(sb + (size_t)row * 64 + kl, Sts + f);
    }
    if (tid < 64) zp[tid] = zpr[(size_t)blk * 64 + tid];
    __syncthreads();

    const int lane = tid & 63, wid = tid >> 6;
    const int wr = wid >> 1, wc = wid & 1;
    const int lrow = lane & 15, lk8 = (lane >> 4) * 8, lr4 = (lane >> 4) * 4;

    // QK^T
    f32x4 accs[2][2] = {};
#pragma unroll
    for (int kin = 0; kin < 64; kin += 32) {
        bf16x8 af[2], bfr[2];
#pragma unroll
        for (int mi = 0; mi < 2; ++mi) {
            const int row = wr * 32 + mi * 16 + lrow;
            af[mi] = *(const bf16x8*)&Qs[row * 64 + SWZ(row, kin + lk8)];
        }
#pragma unroll
        for (int ni = 0; ni < 2; ++ni) {
            const int row = wc * 32 + ni * 16 + lrow;
            bfr[ni] = *(const bf16x8*)&Kns[row * 64 + SWZ(row, kin + lk8)];
        }
#pragma unroll
        for (int mi = 0; mi < 2; ++mi)
#pragma unroll
            for (int ni = 0; ni < 2; ++ni)
                accs[mi][ni] = __builtin_amdgcn_mfma_f32_16x16x32_bf16(
                    af[mi], bfr[ni], accs[mi][ni], 0, 0, 0);
    }

    // mask + bf16 store of scores
#pragma unroll
    for (int mi = 0; mi < 2; ++mi)
#pragma unroll
        for (int ni = 0; ni < 2; ++ni) {
            const int j = wc * 32 + ni * 16 + lrow;
#pragma unroll
            for (int r = 0; r < 4; ++r) {
                const int i = wr * 32 + mi * 16 + lr4 + r;
                const float v = (j <= i) ? accs[mi][ni][r] : 0.f;
                Abf[i * 64 + SWZ(i, j)] = f2bf(v);
            }
        }
    __syncthreads();

    // den[i] = rowsum(A[i][:]) + Q[i].z_prev   (4-way split + combine)
    {
        const int p = tid >> 6, i = tid & 63;
        float s = 0.f;
#pragma unroll
        for (int jj = 0; jj < 16; ++jj) {
            const int j = p * 16 + jj;
            s += bf2f(Abf[i * 64 + SWZ(i, j)]);
            s += bf2f(Qs[i * 64 + SWZ(i, j)]) * zp[j];
        }
        part[p][i] = s;
    }
    __syncthreads();
    if (tid < 64)
        den[tid] = fmaxf(part[0][tid] + part[1][tid] + part[2][tid] + part[3][tid], EPSV);
    __syncthreads();

    // num = A @ V + Q @ S_prev
    f32x4 acco[2][2] = {};
#pragma unroll
    for (int kin = 0; kin < 64; kin += 32) {
        bf16x8 af[2], bfr[2], ag[2], bgr[2];
#pragma unroll
        for (int mi = 0; mi < 2; ++mi) {
            const int row = wr * 32 + mi * 16 + lrow;
            af[mi] = *(const bf16x8*)&Abf[row * 64 + SWZ(row, kin + lk8)];
            ag[mi] = *(const bf16x8*)&Qs[row * 64 + SWZ(row, kin + lk8)];
        }
#pragma unroll
        for (int ni = 0; ni < 2; ++ni) {
            const int row = wc * 32 + ni * 16 + lrow;
            bfr[ni] = *(const bf16x8*)&Vts[row * 64 + SWZ(row, kin + lk8)];
            bgr[ni] = *(const bf16x8*)&Sts[row * 64 + SWZ(row, kin + lk8)];
        }
#pragma unroll
        for (int mi = 0; mi < 2; ++mi)
#pragma unroll
            for (int ni = 0; ni < 2; ++ni) {
                acco[mi][ni] = __builtin_amdgcn_mfma_f32_16x16x32_bf16(
                    af[mi], bfr[ni], acco[mi][ni], 0, 0, 0);
                acco[mi][ni] = __builtin_amdgcn_mfma_f32_16x16x32_bf16(
                    ag[mi], bgr[ni], acco[mi][ni], 0, 0, 0);
            }
    }

    const int b = bh >> 3, h = bh & 7;
#pragma unroll
    for (int mi = 0; mi < 2; ++mi)
#pragma unroll
        for (int ni = 0; ni < 2; ++ni) {
            const int d2 = wc * 32 + ni * 16 + lrow;
#pragma unroll
            for (int r = 0; r < 4; ++r) {
                const int i = wr * 32 + mi * 16 + lr4 + r;
                attn[((size_t)b * TT + t0 + i) * DM + h * HD + d2] =
                    f2bf(acco[mi][ni][r] / den[i]);
            }
        }
}

// ---------------------------------------------------------------------------
extern "C" void kernel_launch(void* const* d_in, const int* in_sizes, int n_in,
                              void* d_out, int out_size, void* d_ws, size_t ws_size,
                              hipStream_t stream)
{
    const float* x  = (const float*)d_in[0];
    const float* Wq = (const float*)d_in[1];
    const float* bq = (const float*)d_in[2];
    const float* Wk = (const float*)d_in[3];
    const float* bk = (const float*)d_in[4];
    const float* Wv = (const float*)d_in[5];
    const float* bv = (const float*)d_in[6];
    const float* Wo = (const float*)d_in[7];
    const float* bo = (const float*)d_in[8];
    float* out = (float*)d_out;

    const size_t SZ = (size_t)BH * TT * HD;        // 2,097,152 elems
    us* xb  = (us*)d_ws;                            // aliased as attn later
    us* WT  = xb + SZ;
    us* qn  = WT + (size_t)4 * DM * DM;
    us* kn  = qn + SZ;
    us* kt  = kn + SZ;
    us* vt  = kt + SZ;
    us* kvc = vt + SZ;
    us* spr = kvc + SZ;
    float* zc  = (float*)(spr + SZ);
    float* zpr = zc + (size_t)BH * NC * 64;
    us* attn = xb;

    prep<<<3072, 256, 0, stream>>>(x, Wq, Wk, Wv, Wo, xb, WT);
    qkv_mfma<<<dim3(ROWS / 64, DM / 128, 3), 256, 0, stream>>>(
        xb, WT, bq, bk, bv, qn, kn, kt, vt);
    chunk_sums<<<BH * NC, 256, 0, stream>>>(kt, vt, kvc, zc);
    scan<<<dim3(BH, 9), 256, 0, stream>>>(kvc, zc, spr, zpr);
    chunk_attn<<<BH * NC, 256, 0, stream>>>(qn, kn, vt, spr, zpr, attn);
    out_mfma<<<dim3(ROWS / 64, DM / 128), 256, 0, stream>>>(
        attn, WT + (size_t)3 * DM * DM, bo, out);
}